// Round 7
// baseline (437.840 us; speedup 1.0000x reference)
//
#include <hip/hip_runtime.h>
#include <hip/hip_bf16.h>

// Problem constants (from reference setup_inputs)
constexpr int B = 128;
constexpr int A = 8732;
constexpr int C = 21;
constexpr int M = 8;

// workspace layout (4-byte elements):
// [0..2] accf  (0=conf_pos, 1=loc_sum, 2=conf_hard_neg)
// [3]    done  (k_topk completion counter)
// [4]    npt   (n_pos_total, written by k_ce block 0)
// [8..8+B)  n_pos
// [8+B ..)  packed/ce_neg buf [B*A]   (offset 544 B -> 16B aligned)

// ---------------------------------------------------------------------------
// K1: per-batch matching. One block (1024 threads) per batch row.
// Block 0 additionally zeroes the accumulators + completion counter (safe:
// nothing in k_match reads them; k_ce/k_topk run in later dispatches).
__global__ __launch_bounds__(1024) void k_match(
    const float* __restrict__ boxes,    // [B,M,4] raw pixel xy
    const int*   __restrict__ labels,   // [B,M]
    const float* __restrict__ anchors,  // [A,4] cxcy
    int*         __restrict__ packed,   // [B,A]  lab | (obj<<8)
    int*         __restrict__ n_pos,    // [B]
    float*       __restrict__ accf,
    int*         __restrict__ done)
{
    __shared__ float         s_iou[A];
    __shared__ unsigned char s_obj[A];
    __shared__ float s_pv[M][16];
    __shared__ int   s_pi[M][16];
    __shared__ int   s_force[M];
    __shared__ int   s_c[16];
    __shared__ float s_box[M][4];
    __shared__ int   s_lab[M];

    const int b = blockIdx.x;
    const int t = threadIdx.x;
    const int lane = t & 63;
    const int wv   = t >> 6;          // 0..15

    if (b == 0 && t == 0) {           // zero accumulators for this iteration
        accf[0] = 0.f; accf[1] = 0.f; accf[2] = 0.f; *done = 0;
    }

    if (t < M * 4) ((float*)s_box)[t] = boxes[b * M * 4 + t];
    if (t < M)     s_lab[t] = labels[b * M + t];
    __syncthreads();

    // scaled boxes (match reference: boxes / 300.0) + areas
    float bb[M][4], barea[M];
#pragma unroll
    for (int m = 0; m < M; m++) {
        bb[m][0] = s_box[m][0] / 300.f;
        bb[m][1] = s_box[m][1] / 300.f;
        bb[m][2] = s_box[m][2] / 300.f;
        bb[m][3] = s_box[m][3] / 300.f;
        barea[m] = (bb[m][2] - bb[m][0]) * (bb[m][3] - bb[m][1]);
    }

    float bestv[M];
    int   besti[M];
#pragma unroll
    for (int m = 0; m < M; m++) { bestv[m] = -1.f; besti[m] = 0; }

    const float4* anch4 = (const float4*)anchors;
    for (int a = t; a < A; a += 1024) {
        float4 an = anch4[a];
        float ax1 = an.x - an.z / 2.0f, ay1 = an.y - an.w / 2.0f;
        float ax2 = an.x + an.z / 2.0f, ay2 = an.y + an.w / 2.0f;
        float aarea = (ax2 - ax1) * (ay2 - ay1);

        float bmax = -1.f; int bm = 0;
#pragma unroll
        for (int m = 0; m < M; m++) {
            float lx = fmaxf(bb[m][0], ax1), ly = fmaxf(bb[m][1], ay1);
            float rx = fminf(bb[m][2], ax2), ry = fminf(bb[m][3], ay2);
            float iw = fmaxf(rx - lx, 0.f), ih = fmaxf(ry - ly, 0.f);
            float inter = iw * ih;
            float iou = inter / (barea[m] + aarea - inter);
            if (iou > bmax) { bmax = iou; bm = m; }               // first-max over m
            if (iou > bestv[m]) { bestv[m] = iou; besti[m] = a; } // first-max over a (ascending)
        }
        s_iou[a] = bmax;
        s_obj[a] = (unsigned char)bm;
    }

    // per-object argmax: wave shuffle reduce (tie-break: smaller anchor index)
#pragma unroll
    for (int m = 0; m < M; m++) {
        float v = bestv[m]; int i = besti[m];
        for (int off = 32; off > 0; off >>= 1) {
            float ov = __shfl_down(v, off);
            int   oi = __shfl_down(i, off);
            if (ov > v || (ov == v && oi < i)) { v = ov; i = oi; }
        }
        if (lane == 0) { s_pv[m][wv] = v; s_pi[m][wv] = i; }
    }
    __syncthreads();

    if (t < M) {
        float bv = -1.f; int bi = 0x7fffffff;
#pragma unroll
        for (int w = 0; w < 16; w++) {
            float v = s_pv[t][w]; int i = s_pi[t][w];
            if (v > bv || (v == bv && i < bi)) { bv = v; bi = i; }
        }
        s_force[t] = bi;
    }
    __syncthreads();

    // numpy fancy-assign semantics: last object wins on duplicate anchors
    if (t == 0) {
        for (int m = 0; m < M; m++) {
            int a = s_force[m];
            s_obj[a] = (unsigned char)m;
            s_iou[a] = 1.0f;
        }
    }
    __syncthreads();

    int cnt = 0;
    for (int a = t; a < A; a += 1024) {
        int obj = s_obj[a];
        int lab = s_lab[obj];
        if (s_iou[a] < 0.5f) lab = 0;
        packed[(size_t)b * A + a] = lab | (obj << 8);
        if (lab != 0) cnt++;
    }
    for (int off = 32; off > 0; off >>= 1) cnt += __shfl_down(cnt, off);
    if (lane == 0) s_c[wv] = cnt;
    __syncthreads();
    if (t == 0) {
        int c0 = 0;
#pragma unroll
        for (int w = 0; w < 16; w++) c0 += s_c[w];
        n_pos[b] = c0;
    }
}

// ---------------------------------------------------------------------------
// K2: per-anchor CE + positive loc L1. ONE ROW PER THREAD, 21 independent
// scalar dword loads.
// Rationale (rounds 0-5 post-mortem): every prior form failed to keep >~4
// VMEM ops in flight per wave — float4-quad needs 84 live floats (> 64 VGPR,
// compiler chunk-serializes), LDS/DMA variants stalled on barriers or wait
// semantics. Row stride is 84 B (not 16B aligned) so scalar dwords are the
// natural unit: 21 floats live = ~40 VGPR total -> all 21 loads issue
// back-to-back with progressive waitcnt, ~5.4 KB in flight per wave.
// Every fetched line is fully consumed (wave's 21 loads tile a contiguous
// 5.4 KB window). Block 0's first wave also reduces n_pos -> npt.
__global__ __launch_bounds__(256) void k_ce(
    const float* __restrict__ plocs,    // [B,A,4]
    const float* __restrict__ pscores,  // [B,A,C]
    const float* __restrict__ boxes,    // [B,M,4] raw pixel xy
    const float* __restrict__ anchors,  // [A,4]
    int*         __restrict__ buf,      // in: packed, out: ce_neg bits
    float*       __restrict__ accf,
    const int*   __restrict__ n_pos,    // [B]
    int*         __restrict__ npt)      // out: n_pos_total
{
    if (blockIdx.x == 0 && threadIdx.x < 64) {
        int v = n_pos[threadIdx.x] + n_pos[threadIdx.x + 64];
        for (int off = 32; off > 0; off >>= 1) v += __shfl_down(v, off);
        if (threadIdx.x == 0) *npt = v;
    }

    // grid covers B*A rows exactly: 4366 blocks * 256 = 1,117,696 = B*A
    const int flat = blockIdx.x * 256 + threadIdx.x;
    float l_pos = 0.f, l_loc = 0.f;

    {
        const int pk = buf[flat];
        const float* row = pscores + (size_t)flat * C;

        float r[21];
#pragma unroll
        for (int c = 0; c < C; c++) r[c] = row[c];   // 21 independent dwords

        const int lab = pk & 255;
        const int obj = pk >> 8;

        float mx = r[0];
#pragma unroll
        for (int c = 1; c < C; c++) mx = fmaxf(mx, r[c]);
        float sum = 0.f, slab = 0.f;
#pragma unroll
        for (int c = 0; c < C; c++) {
            sum += __expf(r[c] - mx);
            if (c == lab) slab = r[c];     // static index, cndmask select
        }
        const float ce = mx + __logf(sum) - slab;

        float cn = ce;
        if (lab != 0) {
            cn = 0.f;
            l_pos = ce;
            const int bi = flat / A;
            const int ai = flat - bi * A;
            const float* bx = boxes + ((size_t)bi * M + obj) * 4;
            const float* an = anchors + (size_t)ai * 4;
            // reference quirk: raw pixel xy boxes fed into cxcy_to_gcxgcy
            float dx = (bx[0] - an[0]) / (an[2] / 10.f);
            float dy = (bx[1] - an[1]) / (an[3] / 10.f);
            float dw = logf(bx[2] / an[2]) * 5.f;
            float dh = logf(bx[3] / an[3]) * 5.f;
            float4 p = ((const float4*)plocs)[flat];
            l_loc = fabsf(p.x - dx) + fabsf(p.y - dy) +
                    fabsf(p.z - dw) + fabsf(p.w - dh);
        }
        ((float*)buf)[flat] = cn;          // coalesced dword store
    }

    // wave reduce; positives are rare so atomics are rare
    for (int off = 32; off > 0; off >>= 1) {
        l_pos += __shfl_down(l_pos, off);
        l_loc += __shfl_down(l_loc, off);
    }
    if ((threadIdx.x & 63) == 0 && (l_pos != 0.f || l_loc != 0.f)) {
        atomicAdd(&accf[0], l_pos);
        atomicAdd(&accf[1], l_loc);
    }
}

// ---------------------------------------------------------------------------
// K3: per-row sum of top-(3*n_pos[b]) of ce_neg via radix select, FUSED with
// the final scalar (completion-counter pattern; device-scope atomics).
// Per-wave histograms whist[16][257] (bank-rotated) avoid the cross-wave
// same-address serialization on the concentrated CE exponent bins.
// Exact even with ties: sum = sum(v>t) + (K - cnt_gt) * t.
__global__ __launch_bounds__(1024) void k_topk(
    const float* __restrict__ ce_neg,   // [B,A] (aliased buf)
    const int*   __restrict__ n_pos,    // [B]
    const int*   __restrict__ npt,      // n_pos_total (from k_ce)
    float*       __restrict__ accf,     // accf[2] += row topK sum
    int*         __restrict__ done,     // completion counter (zeroed by k_match)
    float*       __restrict__ out)
{
    __shared__ unsigned int vals[A];
    __shared__ unsigned int hist[256];      // merged histogram -> suffix sums
    __shared__ unsigned int whist[16][257]; // per-wave histograms (padded)
    __shared__ unsigned int s_prefix, s_krem;
    __shared__ float        rs[16];
    __shared__ unsigned int rc[16];

    const int b = blockIdx.x;
    const int t = threadIdx.x;
    const int lane = t & 63;
    const int wv   = t >> 6;
    const int K = 3 * n_pos[b];
    const float* row = ce_neg + (size_t)b * A;

    {   // coalesced uint4 load (A = 4*2183, row base 16B-aligned)
        const uint4* r4 = (const uint4*)row;
        uint4* v4 = (uint4*)vals;
        for (int i = t; i < A / 4; i += 1024) v4[i] = r4[i];
    }
    if (t == 0) { s_prefix = 0u; s_krem = (unsigned)K; }
    __syncthreads();

    float blockSum = 0.f;                   // valid at t==0

    if (K >= A) {        // uniform branch: sum the whole row
        float s = 0.f;
        for (int i = t; i < A; i += 1024) s += __uint_as_float(vals[i]);
        for (int off = 32; off > 0; off >>= 1) s += __shfl_down(s, off);
        if (lane == 0) rs[wv] = s;
        __syncthreads();
        if (t == 0) {
            float tot = 0.f;
#pragma unroll
            for (int w = 0; w < 16; w++) tot += rs[w];
            blockSum = tot;
        }
    } else if (K > 0) {
        for (int pass = 0; pass < 4; pass++) {
            const int shift = 24 - 8 * pass;
            const unsigned pref = s_prefix;
            const unsigned krem = s_krem;
            // zero per-wave histograms
            unsigned* wf = &whist[0][0];
            for (int i = t; i < 16 * 257; i += 1024) wf[i] = 0u;
            __syncthreads();
            for (int i = t; i < A; i += 1024) {
                unsigned int v = vals[i];
                if (pass == 0 || (v >> (shift + 8)) == pref)
                    atomicAdd(&whist[wv][(v >> shift) & 255u], 1u);
            }
            __syncthreads();
            // merge 16 per-wave hists (lanes read distinct banks, 2/bank)
            if (t < 256) {
                unsigned s = 0;
#pragma unroll
                for (int w = 0; w < 16; w++) s += whist[w][t];
                hist[t] = s;
            }
            __syncthreads();
            // wave-0 suffix scan of the 256 bins (hist[i] := sum hist[i..255])
            if (t < 64) {
                unsigned h0 = hist[4 * t + 0], h1 = hist[4 * t + 1];
                unsigned h2 = hist[4 * t + 2], h3 = hist[4 * t + 3];
                unsigned s3 = h3, s2 = h2 + s3, s1 = h1 + s2, s0 = h0 + s1;
                unsigned suf = s0;                 // inclusive suffix of lane totals
                for (int off = 1; off < 64; off <<= 1) {
                    unsigned o = __shfl_down(suf, off);
                    if (t + off < 64) suf += o;
                }
                unsigned above = suf - s0;         // totals of lanes > t
                hist[4 * t + 0] = above + s0;
                hist[4 * t + 1] = above + s1;
                hist[4 * t + 2] = above + s2;
                hist[4 * t + 3] = above + s3;
            }
            __syncthreads();
            if (t < 256) {
                unsigned ssT = hist[t];
                unsigned ssN = (t < 255) ? hist[t + 1] : 0u;
                if (ssT >= krem && ssN < krem) {   // exactly one thread
                    s_prefix = (pref << 8) | (unsigned)t;
                    s_krem   = krem - ssN;
                }
            }
            __syncthreads();
        }

        const unsigned int tb = s_prefix;  // bits of the K-th largest value
        float sg = 0.f; unsigned int cg = 0;
        for (int i = t; i < A; i += 1024) {
            unsigned int v = vals[i];
            if (v > tb) { sg += __uint_as_float(v); cg++; }
        }
        for (int off = 32; off > 0; off >>= 1) {
            sg += __shfl_down(sg, off);
            cg += __shfl_down(cg, off);
        }
        if (lane == 0) { rs[wv] = sg; rc[wv] = cg; }
        __syncthreads();
        if (t == 0) {
            float tv = __uint_as_float(tb);
            float tot = 0.f; unsigned cnt = 0;
#pragma unroll
            for (int w = 0; w < 16; w++) { tot += rs[w]; cnt += rc[w]; }
            blockSum = tot + (float)(K - (int)cnt) * tv;
        }
    }
    // K <= 0: blockSum stays 0, still participate in completion protocol.

    if (t == 0) {
        if (blockSum != 0.f) atomicAdd(&accf[2], blockSum);
        __threadfence();                       // order my add before the count
        unsigned old = atomicAdd((unsigned*)done, 1u);
        if (old == (unsigned)(B - 1)) {        // last block: final scalar
            float cpos = atomicAdd(&accf[0], 0.f);   // device-coherent reads
            float lsum = atomicAdd(&accf[1], 0.f);
            float chn  = atomicAdd(&accf[2], 0.f);
            float n = (float)(*npt);
            out[0] = (chn + cpos) / n + lsum / (n * 4.f);
        }
    }
}

// ---------------------------------------------------------------------------
extern "C" void kernel_launch(void* const* d_in, const int* in_sizes, int n_in,
                              void* d_out, int out_size, void* d_ws, size_t ws_size,
                              hipStream_t stream)
{
    const float* plocs   = (const float*)d_in[0];  // [B,A,4]
    const float* pscores = (const float*)d_in[1];  // [B,A,C]
    const float* boxes   = (const float*)d_in[2];  // [B,M,4]
    const int*   labels  = (const int*)d_in[3];    // [B,M]
    const float* anchors = (const float*)d_in[4];  // [A,4]
    float*       out     = (float*)d_out;

    float* accf  = (float*)d_ws;
    int*   done  = (int*)d_ws + 3;
    int*   npt   = (int*)d_ws + 4;
    int*   n_pos = (int*)d_ws + 8;
    int*   buf   = (int*)d_ws + 8 + B;

    k_match<<<B, 1024, 0, stream>>>(boxes, labels, anchors, buf, n_pos, accf, done);
    constexpr int NB = (B * A) / 256;              // 4366 blocks, one row/thread
    k_ce<<<NB, 256, 0, stream>>>(plocs, pscores, boxes, anchors,
                                 buf, accf, n_pos, npt);
    k_topk<<<B, 1024, 0, stream>>>((const float*)buf, n_pos, npt, accf, done, out);
}

// Round 8
// 436.775 us; speedup vs baseline: 1.0024x; 1.0024x over previous
//
#include <hip/hip_runtime.h>
#include <hip/hip_bf16.h>

// Problem constants (from reference setup_inputs)
constexpr int B = 128;
constexpr int A = 8732;
constexpr int C = 21;
constexpr int M = 8;

// workspace layout (4-byte elements):
// [0..2] accf  (0=conf_pos, 1=loc_sum, 2=conf_hard_neg)
// [3]    done  (k_topk completion counter)
// [4]    npt   (n_pos_total, written by k_ce block 0)
// [8..8+B)  n_pos
// [8+B ..)  packed/ce_neg buf [B*A]   (offset 544 B -> 16B aligned)

// ---------------------------------------------------------------------------
// K1: per-batch matching. One block (1024 threads) per batch row.
// Block 0 additionally zeroes the accumulators + completion counter (safe:
// nothing in k_match reads them; k_ce/k_topk run in later dispatches).
__global__ __launch_bounds__(1024) void k_match(
    const float* __restrict__ boxes,    // [B,M,4] raw pixel xy
    const int*   __restrict__ labels,   // [B,M]
    const float* __restrict__ anchors,  // [A,4] cxcy
    int*         __restrict__ packed,   // [B,A]  lab | (obj<<8)
    int*         __restrict__ n_pos,    // [B]
    float*       __restrict__ accf,
    int*         __restrict__ done)
{
    __shared__ float         s_iou[A];
    __shared__ unsigned char s_obj[A];
    __shared__ float s_pv[M][16];
    __shared__ int   s_pi[M][16];
    __shared__ int   s_force[M];
    __shared__ int   s_c[16];
    __shared__ float s_box[M][4];
    __shared__ int   s_lab[M];

    const int b = blockIdx.x;
    const int t = threadIdx.x;
    const int lane = t & 63;
    const int wv   = t >> 6;          // 0..15

    if (b == 0 && t == 0) {           // zero accumulators for this iteration
        accf[0] = 0.f; accf[1] = 0.f; accf[2] = 0.f; *done = 0;
    }

    if (t < M * 4) ((float*)s_box)[t] = boxes[b * M * 4 + t];
    if (t < M)     s_lab[t] = labels[b * M + t];
    __syncthreads();

    // scaled boxes (match reference: boxes / 300.0) + areas
    float bb[M][4], barea[M];
#pragma unroll
    for (int m = 0; m < M; m++) {
        bb[m][0] = s_box[m][0] / 300.f;
        bb[m][1] = s_box[m][1] / 300.f;
        bb[m][2] = s_box[m][2] / 300.f;
        bb[m][3] = s_box[m][3] / 300.f;
        barea[m] = (bb[m][2] - bb[m][0]) * (bb[m][3] - bb[m][1]);
    }

    float bestv[M];
    int   besti[M];
#pragma unroll
    for (int m = 0; m < M; m++) { bestv[m] = -1.f; besti[m] = 0; }

    const float4* anch4 = (const float4*)anchors;
    for (int a = t; a < A; a += 1024) {
        float4 an = anch4[a];
        float ax1 = an.x - an.z / 2.0f, ay1 = an.y - an.w / 2.0f;
        float ax2 = an.x + an.z / 2.0f, ay2 = an.y + an.w / 2.0f;
        float aarea = (ax2 - ax1) * (ay2 - ay1);

        float bmax = -1.f; int bm = 0;
#pragma unroll
        for (int m = 0; m < M; m++) {
            float lx = fmaxf(bb[m][0], ax1), ly = fmaxf(bb[m][1], ay1);
            float rx = fminf(bb[m][2], ax2), ry = fminf(bb[m][3], ay2);
            float iw = fmaxf(rx - lx, 0.f), ih = fmaxf(ry - ly, 0.f);
            float inter = iw * ih;
            float iou = inter / (barea[m] + aarea - inter);
            if (iou > bmax) { bmax = iou; bm = m; }               // first-max over m
            if (iou > bestv[m]) { bestv[m] = iou; besti[m] = a; } // first-max over a (ascending)
        }
        s_iou[a] = bmax;
        s_obj[a] = (unsigned char)bm;
    }

    // per-object argmax: wave shuffle reduce (tie-break: smaller anchor index)
#pragma unroll
    for (int m = 0; m < M; m++) {
        float v = bestv[m]; int i = besti[m];
        for (int off = 32; off > 0; off >>= 1) {
            float ov = __shfl_down(v, off);
            int   oi = __shfl_down(i, off);
            if (ov > v || (ov == v && oi < i)) { v = ov; i = oi; }
        }
        if (lane == 0) { s_pv[m][wv] = v; s_pi[m][wv] = i; }
    }
    __syncthreads();

    if (t < M) {
        float bv = -1.f; int bi = 0x7fffffff;
#pragma unroll
        for (int w = 0; w < 16; w++) {
            float v = s_pv[t][w]; int i = s_pi[t][w];
            if (v > bv || (v == bv && i < bi)) { bv = v; bi = i; }
        }
        s_force[t] = bi;
    }
    __syncthreads();

    // numpy fancy-assign semantics: last object wins on duplicate anchors
    if (t == 0) {
        for (int m = 0; m < M; m++) {
            int a = s_force[m];
            s_obj[a] = (unsigned char)m;
            s_iou[a] = 1.0f;
        }
    }
    __syncthreads();

    int cnt = 0;
    for (int a = t; a < A; a += 1024) {
        int obj = s_obj[a];
        int lab = s_lab[obj];
        if (s_iou[a] < 0.5f) lab = 0;
        packed[(size_t)b * A + a] = lab | (obj << 8);
        if (lab != 0) cnt++;
    }
    for (int off = 32; off > 0; off >>= 1) cnt += __shfl_down(cnt, off);
    if (lane == 0) s_c[wv] = cnt;
    __syncthreads();
    if (t == 0) {
        int c0 = 0;
#pragma unroll
        for (int w = 0; w < 16; w++) c0 += s_c[w];
        n_pos[b] = c0;
    }
}

// ---------------------------------------------------------------------------
// K2: per-anchor CE + positive loc L1. Wave-cooperative COALESCED staging,
// NO barriers (rounds 0-7 synthesis):
//  - the quad/scalar forms were bound by per-CU divergent-request processing
//    (~3.2 cy per 16B request, 64 lines per instruction, ~92k requests/CU);
//  - coalesced forms tried so far failed on a block barrier convoy (R1),
//    register spill (R3), or DMA wait semantics (R5).
// This form: each wave owns one 64-row tile (1344 contiguous floats).
//  - 6 coalesced dwordx4 loads (16 lines/instruction -> 16x fewer requests)
//    into NAMED float4 registers (short live ranges, no arrays -> no spill)
//  - write to a wave-PRIVATE LDS strip (5376 B; no __syncthreads anywhere);
//    read back per-row at stride 21 floats (gcd(21,32)=1 -> 2 lanes/bank,
//    conflict-free). Cross-wave TLP (7 blocks/CU at 21.5 KB) hides latency.
// Block 0's first wave also reduces n_pos -> npt.
__global__ __launch_bounds__(256) void k_ce(
    const float* __restrict__ plocs,    // [B,A,4]
    const float* __restrict__ pscores,  // [B,A,C]
    const float* __restrict__ boxes,    // [B,M,4] raw pixel xy
    const float* __restrict__ anchors,  // [A,4]
    int*         __restrict__ buf,      // in: packed, out: ce_neg bits
    float*       __restrict__ accf,
    const int*   __restrict__ n_pos,    // [B]
    int*         __restrict__ npt)      // out: n_pos_total
{
    __shared__ float s[4][1344];        // 4 wave-private strips, 21504 B

    if (blockIdx.x == 0 && threadIdx.x < 64) {
        int v = n_pos[threadIdx.x] + n_pos[threadIdx.x + 64];
        for (int off = 32; off > 0; off >>= 1) v += __shfl_down(v, off);
        if (threadIdx.x == 0) *npt = v;
    }

    const int t    = threadIdx.x;
    const int lane = t & 63;
    const int wv   = t >> 6;
    // grid covers B*A rows exactly: 4366 blocks * 4 waves * 64 rows = B*A
    const int tile = blockIdx.x * 4 + wv;      // one 64-row tile per wave
    const int flat = tile * 64 + lane;         // this thread's row

    float l_pos = 0.f, l_loc = 0.f;

    {
        const float4* src = (const float4*)pscores + (size_t)tile * 336;
        float4* dst = (float4*)s[wv];

        // 6 coalesced loads (5 full-wave + 1 quarter-wave), all independent
        float4 v0 = src[lane];
        float4 v1 = src[lane + 64];
        float4 v2 = src[lane + 128];
        float4 v3 = src[lane + 192];
        float4 v4 = src[lane + 256];
        float4 v5;
        if (lane < 16) v5 = src[320 + lane];
        const int pk = buf[flat];              // coalesced dword

        // stage into wave-private LDS (compiler inserts progressive vmcnt)
        dst[lane]       = v0;
        dst[lane + 64]  = v1;
        dst[lane + 128] = v2;
        dst[lane + 192] = v3;
        dst[lane + 256] = v4;
        if (lane < 16) dst[320 + lane] = v5;

        // per-row read: stride 21 floats, conflict-free; same-wave DS ops
        // are ordered, no barrier needed (wave-private strip)
        const float* row = s[wv] + lane * 21;
        float r[21];
#pragma unroll
        for (int c = 0; c < 21; ++c) r[c] = row[c];

        const int lab = pk & 255;
        const int obj = pk >> 8;

        float mx = r[0];
#pragma unroll
        for (int c = 1; c < 21; ++c) mx = fmaxf(mx, r[c]);
        float sum = 0.f, slab = 0.f;
#pragma unroll
        for (int c = 0; c < 21; ++c) {
            sum += __expf(r[c] - mx);
            if (c == lab) slab = r[c];         // static compare -> cndmask
        }
        const float ce = mx + __logf(sum) - slab;

        float cn = ce;
        if (lab != 0) {
            cn = 0.f;
            l_pos = ce;
            const int bi = flat / A;
            const int ai = flat - bi * A;
            const float* bx = boxes + ((size_t)bi * M + obj) * 4;
            const float* an = anchors + (size_t)ai * 4;
            // reference quirk: raw pixel xy boxes fed into cxcy_to_gcxgcy
            float dx = (bx[0] - an[0]) / (an[2] / 10.f);
            float dy = (bx[1] - an[1]) / (an[3] / 10.f);
            float dw = logf(bx[2] / an[2]) * 5.f;
            float dh = logf(bx[3] / an[3]) * 5.f;
            float4 p = ((const float4*)plocs)[flat];
            l_loc = fabsf(p.x - dx) + fabsf(p.y - dy) +
                    fabsf(p.z - dw) + fabsf(p.w - dh);
        }
        ((float*)buf)[flat] = cn;              // coalesced dword store
    }

    // wave reduce; positives are rare so atomics are rare
    for (int off = 32; off > 0; off >>= 1) {
        l_pos += __shfl_down(l_pos, off);
        l_loc += __shfl_down(l_loc, off);
    }
    if ((t & 63) == 0 && (l_pos != 0.f || l_loc != 0.f)) {
        atomicAdd(&accf[0], l_pos);
        atomicAdd(&accf[1], l_loc);
    }
}

// ---------------------------------------------------------------------------
// K3: per-row sum of top-(3*n_pos[b]) of ce_neg via radix select, FUSED with
// the final scalar (completion-counter pattern; device-scope atomics).
// Per-wave histograms whist[16][257] (bank-rotated) avoid the cross-wave
// same-address serialization on the concentrated CE exponent bins.
// Exact even with ties: sum = sum(v>t) + (K - cnt_gt) * t.
__global__ __launch_bounds__(1024) void k_topk(
    const float* __restrict__ ce_neg,   // [B,A] (aliased buf)
    const int*   __restrict__ n_pos,    // [B]
    const int*   __restrict__ npt,      // n_pos_total (from k_ce)
    float*       __restrict__ accf,     // accf[2] += row topK sum
    int*         __restrict__ done,     // completion counter (zeroed by k_match)
    float*       __restrict__ out)
{
    __shared__ unsigned int vals[A];
    __shared__ unsigned int hist[256];      // merged histogram -> suffix sums
    __shared__ unsigned int whist[16][257]; // per-wave histograms (padded)
    __shared__ unsigned int s_prefix, s_krem;
    __shared__ float        rs[16];
    __shared__ unsigned int rc[16];

    const int b = blockIdx.x;
    const int t = threadIdx.x;
    const int lane = t & 63;
    const int wv   = t >> 6;
    const int K = 3 * n_pos[b];
    const float* row = ce_neg + (size_t)b * A;

    {   // coalesced uint4 load (A = 4*2183, row base 16B-aligned)
        const uint4* r4 = (const uint4*)row;
        uint4* v4 = (uint4*)vals;
        for (int i = t; i < A / 4; i += 1024) v4[i] = r4[i];
    }
    if (t == 0) { s_prefix = 0u; s_krem = (unsigned)K; }
    __syncthreads();

    float blockSum = 0.f;                   // valid at t==0

    if (K >= A) {        // uniform branch: sum the whole row
        float s = 0.f;
        for (int i = t; i < A; i += 1024) s += __uint_as_float(vals[i]);
        for (int off = 32; off > 0; off >>= 1) s += __shfl_down(s, off);
        if (lane == 0) rs[wv] = s;
        __syncthreads();
        if (t == 0) {
            float tot = 0.f;
#pragma unroll
            for (int w = 0; w < 16; w++) tot += rs[w];
            blockSum = tot;
        }
    } else if (K > 0) {
        for (int pass = 0; pass < 4; pass++) {
            const int shift = 24 - 8 * pass;
            const unsigned pref = s_prefix;
            const unsigned krem = s_krem;
            // zero per-wave histograms
            unsigned* wf = &whist[0][0];
            for (int i = t; i < 16 * 257; i += 1024) wf[i] = 0u;
            __syncthreads();
            for (int i = t; i < A; i += 1024) {
                unsigned int v = vals[i];
                if (pass == 0 || (v >> (shift + 8)) == pref)
                    atomicAdd(&whist[wv][(v >> shift) & 255u], 1u);
            }
            __syncthreads();
            // merge 16 per-wave hists (lanes read distinct banks, 2/bank)
            if (t < 256) {
                unsigned s0 = 0;
#pragma unroll
                for (int w = 0; w < 16; w++) s0 += whist[w][t];
                hist[t] = s0;
            }
            __syncthreads();
            // wave-0 suffix scan of the 256 bins (hist[i] := sum hist[i..255])
            if (t < 64) {
                unsigned h0 = hist[4 * t + 0], h1 = hist[4 * t + 1];
                unsigned h2 = hist[4 * t + 2], h3 = hist[4 * t + 3];
                unsigned s3 = h3, s2 = h2 + s3, s1 = h1 + s2, s0 = h0 + s1;
                unsigned suf = s0;                 // inclusive suffix of lane totals
                for (int off = 1; off < 64; off <<= 1) {
                    unsigned o = __shfl_down(suf, off);
                    if (t + off < 64) suf += o;
                }
                unsigned above = suf - s0;         // totals of lanes > t
                hist[4 * t + 0] = above + s0;
                hist[4 * t + 1] = above + s1;
                hist[4 * t + 2] = above + s2;
                hist[4 * t + 3] = above + s3;
            }
            __syncthreads();
            if (t < 256) {
                unsigned ssT = hist[t];
                unsigned ssN = (t < 255) ? hist[t + 1] : 0u;
                if (ssT >= krem && ssN < krem) {   // exactly one thread
                    s_prefix = (pref << 8) | (unsigned)t;
                    s_krem   = krem - ssN;
                }
            }
            __syncthreads();
        }

        const unsigned int tb = s_prefix;  // bits of the K-th largest value
        float sg = 0.f; unsigned int cg = 0;
        for (int i = t; i < A; i += 1024) {
            unsigned int v = vals[i];
            if (v > tb) { sg += __uint_as_float(v); cg++; }
        }
        for (int off = 32; off > 0; off >>= 1) {
            sg += __shfl_down(sg, off);
            cg += __shfl_down(cg, off);
        }
        if (lane == 0) { rs[wv] = sg; rc[wv] = cg; }
        __syncthreads();
        if (t == 0) {
            float tv = __uint_as_float(tb);
            float tot = 0.f; unsigned cnt = 0;
#pragma unroll
            for (int w = 0; w < 16; w++) { tot += rs[w]; cnt += rc[w]; }
            blockSum = tot + (float)(K - (int)cnt) * tv;
        }
    }
    // K <= 0: blockSum stays 0, still participate in completion protocol.

    if (t == 0) {
        if (blockSum != 0.f) atomicAdd(&accf[2], blockSum);
        __threadfence();                       // order my add before the count
        unsigned old = atomicAdd((unsigned*)done, 1u);
        if (old == (unsigned)(B - 1)) {        // last block: final scalar
            float cpos = atomicAdd(&accf[0], 0.f);   // device-coherent reads
            float lsum = atomicAdd(&accf[1], 0.f);
            float chn  = atomicAdd(&accf[2], 0.f);
            float n = (float)(*npt);
            out[0] = (chn + cpos) / n + lsum / (n * 4.f);
        }
    }
}

// ---------------------------------------------------------------------------
extern "C" void kernel_launch(void* const* d_in, const int* in_sizes, int n_in,
                              void* d_out, int out_size, void* d_ws, size_t ws_size,
                              hipStream_t stream)
{
    const float* plocs   = (const float*)d_in[0];  // [B,A,4]
    const float* pscores = (const float*)d_in[1];  // [B,A,C]
    const float* boxes   = (const float*)d_in[2];  // [B,M,4]
    const int*   labels  = (const int*)d_in[3];    // [B,M]
    const float* anchors = (const float*)d_in[4];  // [A,4]
    float*       out     = (float*)d_out;

    float* accf  = (float*)d_ws;
    int*   done  = (int*)d_ws + 3;
    int*   npt   = (int*)d_ws + 4;
    int*   n_pos = (int*)d_ws + 8;
    int*   buf   = (int*)d_ws + 8 + B;

    k_match<<<B, 1024, 0, stream>>>(boxes, labels, anchors, buf, n_pos, accf, done);
    constexpr int NB = (B * A) / (64 * 4);         // 4366 blocks, 1 tile/wave
    k_ce<<<NB, 256, 0, stream>>>(plocs, pscores, boxes, anchors,
                                 buf, accf, n_pos, npt);
    k_topk<<<B, 1024, 0, stream>>>((const float*)buf, n_pos, npt, accf, done, out);
}

// Round 9
// 307.871 us; speedup vs baseline: 1.4222x; 1.4187x over previous
//
#include <hip/hip_runtime.h>
#include <hip/hip_bf16.h>

// Problem constants (from reference setup_inputs)
constexpr int B = 128;
constexpr int A = 8732;
constexpr int C = 21;
constexpr int M = 8;

// workspace layout (4-byte elements):
// [0..2] accf  (0=conf_pos, 1=loc_sum, 2=conf_hard_neg)
// [3]    done  (k_topk completion counter)
// [4]    npt   (n_pos_total, written by k_ce block 0)
// [8..8+B)  n_pos
// [8+B ..)  packed/ce_neg buf [B*A]   (offset 544 B -> 16B aligned)

// ---------------------------------------------------------------------------
// K1: per-batch matching. One block (1024 threads) per batch row.
// Block 0 additionally zeroes the accumulators + completion counter (safe:
// nothing in k_match reads them; k_ce/k_topk run in later dispatches).
__global__ __launch_bounds__(1024) void k_match(
    const float* __restrict__ boxes,    // [B,M,4] raw pixel xy
    const int*   __restrict__ labels,   // [B,M]
    const float* __restrict__ anchors,  // [A,4] cxcy
    int*         __restrict__ packed,   // [B,A]  lab | (obj<<8)
    int*         __restrict__ n_pos,    // [B]
    float*       __restrict__ accf,
    int*         __restrict__ done)
{
    __shared__ float         s_iou[A];
    __shared__ unsigned char s_obj[A];
    __shared__ float s_pv[M][16];
    __shared__ int   s_pi[M][16];
    __shared__ int   s_force[M];
    __shared__ int   s_c[16];
    __shared__ float s_box[M][4];
    __shared__ int   s_lab[M];

    const int b = blockIdx.x;
    const int t = threadIdx.x;
    const int lane = t & 63;
    const int wv   = t >> 6;          // 0..15

    if (b == 0 && t == 0) {           // zero accumulators for this iteration
        accf[0] = 0.f; accf[1] = 0.f; accf[2] = 0.f; *done = 0;
    }

    if (t < M * 4) ((float*)s_box)[t] = boxes[b * M * 4 + t];
    if (t < M)     s_lab[t] = labels[b * M + t];
    __syncthreads();

    // scaled boxes (match reference: boxes / 300.0) + areas
    float bb[M][4], barea[M];
#pragma unroll
    for (int m = 0; m < M; m++) {
        bb[m][0] = s_box[m][0] / 300.f;
        bb[m][1] = s_box[m][1] / 300.f;
        bb[m][2] = s_box[m][2] / 300.f;
        bb[m][3] = s_box[m][3] / 300.f;
        barea[m] = (bb[m][2] - bb[m][0]) * (bb[m][3] - bb[m][1]);
    }

    float bestv[M];
    int   besti[M];
#pragma unroll
    for (int m = 0; m < M; m++) { bestv[m] = -1.f; besti[m] = 0; }

    const float4* anch4 = (const float4*)anchors;
    for (int a = t; a < A; a += 1024) {
        float4 an = anch4[a];
        float ax1 = an.x - an.z / 2.0f, ay1 = an.y - an.w / 2.0f;
        float ax2 = an.x + an.z / 2.0f, ay2 = an.y + an.w / 2.0f;
        float aarea = (ax2 - ax1) * (ay2 - ay1);

        float bmax = -1.f; int bm = 0;
#pragma unroll
        for (int m = 0; m < M; m++) {
            float lx = fmaxf(bb[m][0], ax1), ly = fmaxf(bb[m][1], ay1);
            float rx = fminf(bb[m][2], ax2), ry = fminf(bb[m][3], ay2);
            float iw = fmaxf(rx - lx, 0.f), ih = fmaxf(ry - ly, 0.f);
            float inter = iw * ih;
            float iou = inter / (barea[m] + aarea - inter);
            if (iou > bmax) { bmax = iou; bm = m; }               // first-max over m
            if (iou > bestv[m]) { bestv[m] = iou; besti[m] = a; } // first-max over a (ascending)
        }
        s_iou[a] = bmax;
        s_obj[a] = (unsigned char)bm;
    }

    // per-object argmax: wave shuffle reduce (tie-break: smaller anchor index)
#pragma unroll
    for (int m = 0; m < M; m++) {
        float v = bestv[m]; int i = besti[m];
        for (int off = 32; off > 0; off >>= 1) {
            float ov = __shfl_down(v, off);
            int   oi = __shfl_down(i, off);
            if (ov > v || (ov == v && oi < i)) { v = ov; i = oi; }
        }
        if (lane == 0) { s_pv[m][wv] = v; s_pi[m][wv] = i; }
    }
    __syncthreads();

    if (t < M) {
        float bv = -1.f; int bi = 0x7fffffff;
#pragma unroll
        for (int w = 0; w < 16; w++) {
            float v = s_pv[t][w]; int i = s_pi[t][w];
            if (v > bv || (v == bv && i < bi)) { bv = v; bi = i; }
        }
        s_force[t] = bi;
    }
    __syncthreads();

    // numpy fancy-assign semantics: last object wins on duplicate anchors
    if (t == 0) {
        for (int m = 0; m < M; m++) {
            int a = s_force[m];
            s_obj[a] = (unsigned char)m;
            s_iou[a] = 1.0f;
        }
    }
    __syncthreads();

    int cnt = 0;
    for (int a = t; a < A; a += 1024) {
        int obj = s_obj[a];
        int lab = s_lab[obj];
        if (s_iou[a] < 0.5f) lab = 0;
        packed[(size_t)b * A + a] = lab | (obj << 8);
        if (lab != 0) cnt++;
    }
    for (int off = 32; off > 0; off >>= 1) cnt += __shfl_down(cnt, off);
    if (lane == 0) s_c[wv] = cnt;
    __syncthreads();
    if (t == 0) {
        int c0 = 0;
#pragma unroll
        for (int w = 0; w < 16; w++) c0 += s_c[w];
        n_pos[b] = c0;
    }
}

// ---------------------------------------------------------------------------
// K2: per-anchor CE + positive loc L1. One thread per 4 consecutive anchors
// (best measured form, 122 µs; 5 alternative structures all >= this).
// SPLIT into two half-grid launches (blk0 = block offset) so each dispatch
// is ~61 µs: any kernel slower than that must surface in the rocprof top-5 —
// this is how we finally get k_match/k_topk counters.
__global__ __launch_bounds__(256) void k_ce(
    const float* __restrict__ plocs,    // [B,A,4]
    const float* __restrict__ pscores,  // [B,A,C]
    const float* __restrict__ boxes,    // [B,M,4] raw pixel xy
    const float* __restrict__ anchors,  // [A,4]
    int*         __restrict__ buf,      // in: packed, out: ce_neg bits
    float*       __restrict__ accf,
    const int*   __restrict__ n_pos,    // [B]
    int*         __restrict__ npt,      // out: n_pos_total
    int          blk0)                  // block offset of this half
{
    if (blk0 == 0 && blockIdx.x == 0 && threadIdx.x < 64) {
        int v = n_pos[threadIdx.x] + n_pos[threadIdx.x + 64];
        for (int off = 32; off > 0; off >>= 1) v += __shfl_down(v, off);
        if (threadIdx.x == 0) *npt = v;
    }

    constexpr int NQ = B * A / 4;       // 279424 quads
    const int i4 = (blk0 + blockIdx.x) * 256 + threadIdx.x;
    float l_pos = 0.f, l_loc = 0.f;

    if (i4 < NQ) {
        const int base = i4 * 4;        // flat anchor index of quad start
        const float4* s4 = (const float4*)(pscores + (size_t)base * C);
        float4 v[21];
#pragma unroll
        for (int i = 0; i < 21; i++) v[i] = s4[i];   // 336 B contiguous
        const float* f = (const float*)v;            // 84 floats

        int4 pk4 = ((const int4*)buf)[i4];
        const int pks[4] = {pk4.x, pk4.y, pk4.z, pk4.w};

        const int b = base / A;
        const int a0 = base - b * A;

        float4 cn4;
        float* cn = (float*)&cn4;
#pragma unroll
        for (int j = 0; j < 4; j++) {
            const float* row = f + j * C;
            const int lab = pks[j] & 255;
            const int obj = pks[j] >> 8;

            float mx = row[0];
#pragma unroll
            for (int c = 1; c < C; c++) mx = fmaxf(mx, row[c]);
            float sum = 0.f, slab = 0.f;
#pragma unroll
            for (int c = 0; c < C; c++) {
                sum += __expf(row[c] - mx);
                if (c == lab) slab = row[c];
            }
            float ce = mx + __logf(sum) - slab;

            cn[j] = ce;
            if (lab != 0) {
                cn[j] = 0.f;
                l_pos += ce;
                const float* bx = boxes + ((size_t)b * M + obj) * 4;
                const float* an = anchors + (size_t)(a0 + j) * 4;
                // reference quirk: raw pixel xy boxes fed into cxcy_to_gcxgcy
                float dx = (bx[0] - an[0]) / (an[2] / 10.f);
                float dy = (bx[1] - an[1]) / (an[3] / 10.f);
                float dw = logf(bx[2] / an[2]) * 5.f;
                float dh = logf(bx[3] / an[3]) * 5.f;
                float4 p = ((const float4*)plocs)[base + j];
                l_loc += fabsf(p.x - dx) + fabsf(p.y - dy) +
                         fabsf(p.z - dw) + fabsf(p.w - dh);
            }
        }
        ((float4*)buf)[i4] = cn4;
    }

    // wave reduce; positives are rare so atomics are rare
    for (int off = 32; off > 0; off >>= 1) {
        l_pos += __shfl_down(l_pos, off);
        l_loc += __shfl_down(l_loc, off);
    }
    if ((threadIdx.x & 63) == 0 && (l_pos != 0.f || l_loc != 0.f)) {
        atomicAdd(&accf[0], l_pos);
        atomicAdd(&accf[1], l_loc);
    }
}

// ---------------------------------------------------------------------------
// K3: per-row sum of top-(3*n_pos[b]) of ce_neg via radix select, FUSED with
// the final scalar (completion-counter pattern; device-scope atomics).
// 512 threads (was 1024): same algorithm, half the barrier waves and half
// the per-wave histogram zero/merge cost. whist[8][257] bank-rotated.
// Exact even with ties: sum = sum(v>t) + (K - cnt_gt) * t.
__global__ __launch_bounds__(512) void k_topk(
    const float* __restrict__ ce_neg,   // [B,A] (aliased buf)
    const int*   __restrict__ n_pos,    // [B]
    const int*   __restrict__ npt,      // n_pos_total (from k_ce)
    float*       __restrict__ accf,     // accf[2] += row topK sum
    int*         __restrict__ done,     // completion counter (zeroed by k_match)
    float*       __restrict__ out)
{
    __shared__ unsigned int vals[A];
    __shared__ unsigned int hist[256];      // merged histogram -> suffix sums
    __shared__ unsigned int whist[8][257];  // per-wave histograms (padded)
    __shared__ unsigned int s_prefix, s_krem;
    __shared__ float        rs[8];
    __shared__ unsigned int rc[8];

    const int b = blockIdx.x;
    const int t = threadIdx.x;
    const int lane = t & 63;
    const int wv   = t >> 6;               // 0..7
    const int K = 3 * n_pos[b];
    const float* row = ce_neg + (size_t)b * A;

    {   // coalesced uint4 load (A = 4*2183, row base 16B-aligned)
        const uint4* r4 = (const uint4*)row;
        uint4* v4 = (uint4*)vals;
        for (int i = t; i < A / 4; i += 512) v4[i] = r4[i];
    }
    if (t == 0) { s_prefix = 0u; s_krem = (unsigned)K; }
    __syncthreads();

    float blockSum = 0.f;                   // valid at t==0

    if (K >= A) {        // uniform branch: sum the whole row
        float s = 0.f;
        for (int i = t; i < A; i += 512) s += __uint_as_float(vals[i]);
        for (int off = 32; off > 0; off >>= 1) s += __shfl_down(s, off);
        if (lane == 0) rs[wv] = s;
        __syncthreads();
        if (t == 0) {
            float tot = 0.f;
#pragma unroll
            for (int w = 0; w < 8; w++) tot += rs[w];
            blockSum = tot;
        }
    } else if (K > 0) {
        for (int pass = 0; pass < 4; pass++) {
            const int shift = 24 - 8 * pass;
            const unsigned pref = s_prefix;
            const unsigned krem = s_krem;
            // zero per-wave histograms
            unsigned* wf = &whist[0][0];
            for (int i = t; i < 8 * 257; i += 512) wf[i] = 0u;
            __syncthreads();
            for (int i = t; i < A; i += 512) {
                unsigned int v = vals[i];
                if (pass == 0 || (v >> (shift + 8)) == pref)
                    atomicAdd(&whist[wv][(v >> shift) & 255u], 1u);
            }
            __syncthreads();
            // merge 8 per-wave hists
            if (t < 256) {
                unsigned s0 = 0;
#pragma unroll
                for (int w = 0; w < 8; w++) s0 += whist[w][t];
                hist[t] = s0;
            }
            __syncthreads();
            // wave-0 suffix scan of the 256 bins (hist[i] := sum hist[i..255])
            if (t < 64) {
                unsigned h0 = hist[4 * t + 0], h1 = hist[4 * t + 1];
                unsigned h2 = hist[4 * t + 2], h3 = hist[4 * t + 3];
                unsigned s3 = h3, s2 = h2 + s3, s1 = h1 + s2, s0 = h0 + s1;
                unsigned suf = s0;                 // inclusive suffix of lane totals
                for (int off = 1; off < 64; off <<= 1) {
                    unsigned o = __shfl_down(suf, off);
                    if (t + off < 64) suf += o;
                }
                unsigned above = suf - s0;         // totals of lanes > t
                hist[4 * t + 0] = above + s0;
                hist[4 * t + 1] = above + s1;
                hist[4 * t + 2] = above + s2;
                hist[4 * t + 3] = above + s3;
            }
            __syncthreads();
            if (t < 256) {
                unsigned ssT = hist[t];
                unsigned ssN = (t < 255) ? hist[t + 1] : 0u;
                if (ssT >= krem && ssN < krem) {   // exactly one thread
                    s_prefix = (pref << 8) | (unsigned)t;
                    s_krem   = krem - ssN;
                }
            }
            __syncthreads();
        }

        const unsigned int tb = s_prefix;  // bits of the K-th largest value
        float sg = 0.f; unsigned int cg = 0;
        for (int i = t; i < A; i += 512) {
            unsigned int v = vals[i];
            if (v > tb) { sg += __uint_as_float(v); cg++; }
        }
        for (int off = 32; off > 0; off >>= 1) {
            sg += __shfl_down(sg, off);
            cg += __shfl_down(cg, off);
        }
        if (lane == 0) { rs[wv] = sg; rc[wv] = cg; }
        __syncthreads();
        if (t == 0) {
            float tv = __uint_as_float(tb);
            float tot = 0.f; unsigned cnt = 0;
#pragma unroll
            for (int w = 0; w < 8; w++) { tot += rs[w]; cnt += rc[w]; }
            blockSum = tot + (float)(K - (int)cnt) * tv;
        }
    }
    // K <= 0: blockSum stays 0, still participate in completion protocol.

    if (t == 0) {
        if (blockSum != 0.f) atomicAdd(&accf[2], blockSum);
        __threadfence();                       // order my add before the count
        unsigned old = atomicAdd((unsigned*)done, 1u);
        if (old == (unsigned)(B - 1)) {        // last block: final scalar
            float cpos = atomicAdd(&accf[0], 0.f);   // device-coherent reads
            float lsum = atomicAdd(&accf[1], 0.f);
            float chn  = atomicAdd(&accf[2], 0.f);
            float n = (float)(*npt);
            out[0] = (chn + cpos) / n + lsum / (n * 4.f);
        }
    }
}

// ---------------------------------------------------------------------------
extern "C" void kernel_launch(void* const* d_in, const int* in_sizes, int n_in,
                              void* d_out, int out_size, void* d_ws, size_t ws_size,
                              hipStream_t stream)
{
    const float* plocs   = (const float*)d_in[0];  // [B,A,4]
    const float* pscores = (const float*)d_in[1];  // [B,A,C]
    const float* boxes   = (const float*)d_in[2];  // [B,M,4]
    const int*   labels  = (const int*)d_in[3];    // [B,M]
    const float* anchors = (const float*)d_in[4];  // [A,4]
    float*       out     = (float*)d_out;

    float* accf  = (float*)d_ws;
    int*   done  = (int*)d_ws + 3;
    int*   npt   = (int*)d_ws + 4;
    int*   n_pos = (int*)d_ws + 8;
    int*   buf   = (int*)d_ws + 8 + B;

    k_match<<<B, 1024, 0, stream>>>(boxes, labels, anchors, buf, n_pos, accf, done);
    constexpr int NQ  = B * A / 4;                 // 279424 quads
    constexpr int NB  = (NQ + 255) / 256;          // 1092 blocks total
    constexpr int NB0 = NB / 2;                    // 546 + 546
    k_ce<<<NB0, 256, 0, stream>>>(plocs, pscores, boxes, anchors,
                                  buf, accf, n_pos, npt, 0);
    k_ce<<<NB - NB0, 256, 0, stream>>>(plocs, pscores, boxes, anchors,
                                       buf, accf, n_pos, npt, NB0);
    k_topk<<<B, 512, 0, stream>>>((const float*)buf, n_pos, npt, accf, done, out);
}

// Round 11
// 304.071 us; speedup vs baseline: 1.4399x; 1.0125x over previous
//
#include <hip/hip_runtime.h>
#include <hip/hip_bf16.h>

// Problem constants (from reference setup_inputs)
constexpr int B = 128;
constexpr int A = 8732;
constexpr int C = 21;
constexpr int M = 8;

// native clang vector type for __builtin_nontemporal_load (HIP_vector_type
// float4 is rejected by the builtin's type check)
typedef float f4_t __attribute__((ext_vector_type(4)));

// workspace layout (4-byte elements):
// [0..2] accf  (0=conf_pos, 1=loc_sum, 2=conf_hard_neg)
// [3]    done  (k_topk completion counter)
// [4]    npt   (n_pos_total, written by k_ce block 0)
// [8..8+B)  n_pos
// [8+B ..)  packed/ce_neg buf [B*A]   (offset 544 B -> 16B aligned)

// ---------------------------------------------------------------------------
// K1: per-batch matching. One block (1024 threads) per batch row.
// Block 0 additionally zeroes the accumulators + completion counter (safe:
// nothing in k_match reads them; k_ce/k_topk run in later dispatches).
__global__ __launch_bounds__(1024) void k_match(
    const float* __restrict__ boxes,    // [B,M,4] raw pixel xy
    const int*   __restrict__ labels,   // [B,M]
    const float* __restrict__ anchors,  // [A,4] cxcy
    int*         __restrict__ packed,   // [B,A]  lab | (obj<<8)
    int*         __restrict__ n_pos,    // [B]
    float*       __restrict__ accf,
    int*         __restrict__ done)
{
    __shared__ float         s_iou[A];
    __shared__ unsigned char s_obj[A];
    __shared__ float s_pv[M][16];
    __shared__ int   s_pi[M][16];
    __shared__ int   s_force[M];
    __shared__ int   s_c[16];
    __shared__ float s_box[M][4];
    __shared__ int   s_lab[M];

    const int b = blockIdx.x;
    const int t = threadIdx.x;
    const int lane = t & 63;
    const int wv   = t >> 6;          // 0..15

    if (b == 0 && t == 0) {           // zero accumulators for this iteration
        accf[0] = 0.f; accf[1] = 0.f; accf[2] = 0.f; *done = 0;
    }

    if (t < M * 4) ((float*)s_box)[t] = boxes[b * M * 4 + t];
    if (t < M)     s_lab[t] = labels[b * M + t];
    __syncthreads();

    // scaled boxes (match reference: boxes / 300.0) + areas
    float bb[M][4], barea[M];
#pragma unroll
    for (int m = 0; m < M; m++) {
        bb[m][0] = s_box[m][0] / 300.f;
        bb[m][1] = s_box[m][1] / 300.f;
        bb[m][2] = s_box[m][2] / 300.f;
        bb[m][3] = s_box[m][3] / 300.f;
        barea[m] = (bb[m][2] - bb[m][0]) * (bb[m][3] - bb[m][1]);
    }

    float bestv[M];
    int   besti[M];
#pragma unroll
    for (int m = 0; m < M; m++) { bestv[m] = -1.f; besti[m] = 0; }

    const float4* anch4 = (const float4*)anchors;
    for (int a = t; a < A; a += 1024) {
        float4 an = anch4[a];
        float ax1 = an.x - an.z / 2.0f, ay1 = an.y - an.w / 2.0f;
        float ax2 = an.x + an.z / 2.0f, ay2 = an.y + an.w / 2.0f;
        float aarea = (ax2 - ax1) * (ay2 - ay1);

        float bmax = -1.f; int bm = 0;
#pragma unroll
        for (int m = 0; m < M; m++) {
            float lx = fmaxf(bb[m][0], ax1), ly = fmaxf(bb[m][1], ay1);
            float rx = fminf(bb[m][2], ax2), ry = fminf(bb[m][3], ay2);
            float iw = fmaxf(rx - lx, 0.f), ih = fmaxf(ry - ly, 0.f);
            float inter = iw * ih;
            float iou = inter / (barea[m] + aarea - inter);
            if (iou > bmax) { bmax = iou; bm = m; }               // first-max over m
            if (iou > bestv[m]) { bestv[m] = iou; besti[m] = a; } // first-max over a (ascending)
        }
        s_iou[a] = bmax;
        s_obj[a] = (unsigned char)bm;
    }

    // per-object argmax: wave shuffle reduce (tie-break: smaller anchor index)
#pragma unroll
    for (int m = 0; m < M; m++) {
        float v = bestv[m]; int i = besti[m];
        for (int off = 32; off > 0; off >>= 1) {
            float ov = __shfl_down(v, off);
            int   oi = __shfl_down(i, off);
            if (ov > v || (ov == v && oi < i)) { v = ov; i = oi; }
        }
        if (lane == 0) { s_pv[m][wv] = v; s_pi[m][wv] = i; }
    }
    __syncthreads();

    if (t < M) {
        float bv = -1.f; int bi = 0x7fffffff;
#pragma unroll
        for (int w = 0; w < 16; w++) {
            float v = s_pv[t][w]; int i = s_pi[t][w];
            if (v > bv || (v == bv && i < bi)) { bv = v; bi = i; }
        }
        s_force[t] = bi;
    }
    __syncthreads();

    // numpy fancy-assign semantics: last object wins on duplicate anchors
    if (t == 0) {
        for (int m = 0; m < M; m++) {
            int a = s_force[m];
            s_obj[a] = (unsigned char)m;
            s_iou[a] = 1.0f;
        }
    }
    __syncthreads();

    int cnt = 0;
    for (int a = t; a < A; a += 1024) {
        int obj = s_obj[a];
        int lab = s_lab[obj];
        if (s_iou[a] < 0.5f) lab = 0;
        packed[(size_t)b * A + a] = lab | (obj << 8);
        if (lab != 0) cnt++;
    }
    for (int off = 32; off > 0; off >>= 1) cnt += __shfl_down(cnt, off);
    if (lane == 0) s_c[wv] = cnt;
    __syncthreads();
    if (t == 0) {
        int c0 = 0;
#pragma unroll
        for (int w = 0; w < 16; w++) c0 += s_c[w];
        n_pos[b] = c0;
    }
}

// ---------------------------------------------------------------------------
// K2: per-anchor CE + positive loc L1. One thread per 4 consecutive anchors:
// 84 floats = 21 aligned float4 loads (best measured form across 6 tried
// structures; all healthy alternatives land at the same ~122 µs floor).
// pscores loads are NONTEMPORAL (94 MB, read exactly once, zero reuse) —
// bypass L1/L2 allocation, keep cache for buf/plocs/anchors. Uses the native
// ext_vector_type(4) float, the only vector type the builtin accepts.
// Block 0's first wave reduces n_pos -> npt.
__global__ __launch_bounds__(256) void k_ce(
    const float* __restrict__ plocs,    // [B,A,4]
    const float* __restrict__ pscores,  // [B,A,C]
    const float* __restrict__ boxes,    // [B,M,4] raw pixel xy
    const float* __restrict__ anchors,  // [A,4]
    int*         __restrict__ buf,      // in: packed, out: ce_neg bits
    float*       __restrict__ accf,
    const int*   __restrict__ n_pos,    // [B]
    int*         __restrict__ npt)      // out: n_pos_total
{
    if (blockIdx.x == 0 && threadIdx.x < 64) {
        int v = n_pos[threadIdx.x] + n_pos[threadIdx.x + 64];
        for (int off = 32; off > 0; off >>= 1) v += __shfl_down(v, off);
        if (threadIdx.x == 0) *npt = v;
    }

    constexpr int NQ = B * A / 4;       // 279424 quads
    const int i4 = blockIdx.x * 256 + threadIdx.x;
    float l_pos = 0.f, l_loc = 0.f;

    if (i4 < NQ) {
        const int base = i4 * 4;        // flat anchor index of quad start
        const f4_t* s4 = (const f4_t*)(pscores + (size_t)base * C);
        f4_t v[21];
#pragma unroll
        for (int i = 0; i < 21; i++) v[i] = __builtin_nontemporal_load(s4 + i);
        const float* f = (const float*)v;            // 84 floats

        int4 pk4 = ((const int4*)buf)[i4];
        const int pks[4] = {pk4.x, pk4.y, pk4.z, pk4.w};

        const int b = base / A;
        const int a0 = base - b * A;

        float4 cn4;
        float* cn = (float*)&cn4;
#pragma unroll
        for (int j = 0; j < 4; j++) {
            const float* row = f + j * C;
            const int lab = pks[j] & 255;
            const int obj = pks[j] >> 8;

            float mx = row[0];
#pragma unroll
            for (int c = 1; c < C; c++) mx = fmaxf(mx, row[c]);
            float sum = 0.f, slab = 0.f;
#pragma unroll
            for (int c = 0; c < C; c++) {
                sum += __expf(row[c] - mx);
                if (c == lab) slab = row[c];
            }
            float ce = mx + __logf(sum) - slab;

            cn[j] = ce;
            if (lab != 0) {
                cn[j] = 0.f;
                l_pos += ce;
                const float* bx = boxes + ((size_t)b * M + obj) * 4;
                const float* an = anchors + (size_t)(a0 + j) * 4;
                // reference quirk: raw pixel xy boxes fed into cxcy_to_gcxgcy
                float dx = (bx[0] - an[0]) / (an[2] / 10.f);
                float dy = (bx[1] - an[1]) / (an[3] / 10.f);
                float dw = logf(bx[2] / an[2]) * 5.f;
                float dh = logf(bx[3] / an[3]) * 5.f;
                float4 p = ((const float4*)plocs)[base + j];
                l_loc += fabsf(p.x - dx) + fabsf(p.y - dy) +
                         fabsf(p.z - dw) + fabsf(p.w - dh);
            }
        }
        ((float4*)buf)[i4] = cn4;
    }

    // wave reduce; positives are rare so atomics are rare
    for (int off = 32; off > 0; off >>= 1) {
        l_pos += __shfl_down(l_pos, off);
        l_loc += __shfl_down(l_loc, off);
    }
    if ((threadIdx.x & 63) == 0 && (l_pos != 0.f || l_loc != 0.f)) {
        atomicAdd(&accf[0], l_pos);
        atomicAdd(&accf[1], l_loc);
    }
}

// ---------------------------------------------------------------------------
// K3: per-row sum of top-(3*n_pos[b]) of ce_neg via radix select, FUSED with
// the final scalar (completion-counter pattern; device-scope atomics).
// Per-wave histograms whist[8][257] (bank-rotated) avoid cross-wave
// same-address serialization on the concentrated CE exponent bins.
// Exact even with ties: sum = sum(v>t) + (K - cnt_gt) * t.
__global__ __launch_bounds__(512) void k_topk(
    const float* __restrict__ ce_neg,   // [B,A] (aliased buf)
    const int*   __restrict__ n_pos,    // [B]
    const int*   __restrict__ npt,      // n_pos_total (from k_ce)
    float*       __restrict__ accf,     // accf[2] += row topK sum
    int*         __restrict__ done,     // completion counter (zeroed by k_match)
    float*       __restrict__ out)
{
    __shared__ unsigned int vals[A];
    __shared__ unsigned int hist[256];      // merged histogram -> suffix sums
    __shared__ unsigned int whist[8][257];  // per-wave histograms (padded)
    __shared__ unsigned int s_prefix, s_krem;
    __shared__ float        rs[8];
    __shared__ unsigned int rc[8];

    const int b = blockIdx.x;
    const int t = threadIdx.x;
    const int lane = t & 63;
    const int wv   = t >> 6;               // 0..7
    const int K = 3 * n_pos[b];
    const float* row = ce_neg + (size_t)b * A;

    {   // coalesced uint4 load (A = 4*2183, row base 16B-aligned)
        const uint4* r4 = (const uint4*)row;
        uint4* v4 = (uint4*)vals;
        for (int i = t; i < A / 4; i += 512) v4[i] = r4[i];
    }
    if (t == 0) { s_prefix = 0u; s_krem = (unsigned)K; }
    __syncthreads();

    float blockSum = 0.f;                   // valid at t==0

    if (K >= A) {        // uniform branch: sum the whole row
        float s = 0.f;
        for (int i = t; i < A; i += 512) s += __uint_as_float(vals[i]);
        for (int off = 32; off > 0; off >>= 1) s += __shfl_down(s, off);
        if (lane == 0) rs[wv] = s;
        __syncthreads();
        if (t == 0) {
            float tot = 0.f;
#pragma unroll
            for (int w = 0; w < 8; w++) tot += rs[w];
            blockSum = tot;
        }
    } else if (K > 0) {
        for (int pass = 0; pass < 4; pass++) {
            const int shift = 24 - 8 * pass;
            const unsigned pref = s_prefix;
            const unsigned krem = s_krem;
            // zero per-wave histograms
            unsigned* wf = &whist[0][0];
            for (int i = t; i < 8 * 257; i += 512) wf[i] = 0u;
            __syncthreads();
            for (int i = t; i < A; i += 512) {
                unsigned int v = vals[i];
                if (pass == 0 || (v >> (shift + 8)) == pref)
                    atomicAdd(&whist[wv][(v >> shift) & 255u], 1u);
            }
            __syncthreads();
            // merge 8 per-wave hists
            if (t < 256) {
                unsigned s0 = 0;
#pragma unroll
                for (int w = 0; w < 8; w++) s0 += whist[w][t];
                hist[t] = s0;
            }
            __syncthreads();
            // wave-0 suffix scan of the 256 bins (hist[i] := sum hist[i..255])
            if (t < 64) {
                unsigned h0 = hist[4 * t + 0], h1 = hist[4 * t + 1];
                unsigned h2 = hist[4 * t + 2], h3 = hist[4 * t + 3];
                unsigned s3 = h3, s2 = h2 + s3, s1 = h1 + s2, s0 = h0 + s1;
                unsigned suf = s0;                 // inclusive suffix of lane totals
                for (int off = 1; off < 64; off <<= 1) {
                    unsigned o = __shfl_down(suf, off);
                    if (t + off < 64) suf += o;
                }
                unsigned above = suf - s0;         // totals of lanes > t
                hist[4 * t + 0] = above + s0;
                hist[4 * t + 1] = above + s1;
                hist[4 * t + 2] = above + s2;
                hist[4 * t + 3] = above + s3;
            }
            __syncthreads();
            if (t < 256) {
                unsigned ssT = hist[t];
                unsigned ssN = (t < 255) ? hist[t + 1] : 0u;
                if (ssT >= krem && ssN < krem) {   // exactly one thread
                    s_prefix = (pref << 8) | (unsigned)t;
                    s_krem   = krem - ssN;
                }
            }
            __syncthreads();
        }

        const unsigned int tb = s_prefix;  // bits of the K-th largest value
        float sg = 0.f; unsigned int cg = 0;
        for (int i = t; i < A; i += 512) {
            unsigned int v = vals[i];
            if (v > tb) { sg += __uint_as_float(v); cg++; }
        }
        for (int off = 32; off > 0; off >>= 1) {
            sg += __shfl_down(sg, off);
            cg += __shfl_down(cg, off);
        }
        if (lane == 0) { rs[wv] = sg; rc[wv] = cg; }
        __syncthreads();
        if (t == 0) {
            float tv = __uint_as_float(tb);
            float tot = 0.f; unsigned cnt = 0;
#pragma unroll
            for (int w = 0; w < 8; w++) { tot += rs[w]; cnt += rc[w]; }
            blockSum = tot + (float)(K - (int)cnt) * tv;
        }
    }
    // K <= 0: blockSum stays 0, still participate in completion protocol.

    if (t == 0) {
        if (blockSum != 0.f) atomicAdd(&accf[2], blockSum);
        __threadfence();                       // order my add before the count
        unsigned old = atomicAdd((unsigned*)done, 1u);
        if (old == (unsigned)(B - 1)) {        // last block: final scalar
            float cpos = atomicAdd(&accf[0], 0.f);   // device-coherent reads
            float lsum = atomicAdd(&accf[1], 0.f);
            float chn  = atomicAdd(&accf[2], 0.f);
            float n = (float)(*npt);
            out[0] = (chn + cpos) / n + lsum / (n * 4.f);
        }
    }
}

// ---------------------------------------------------------------------------
extern "C" void kernel_launch(void* const* d_in, const int* in_sizes, int n_in,
                              void* d_out, int out_size, void* d_ws, size_t ws_size,
                              hipStream_t stream)
{
    const float* plocs   = (const float*)d_in[0];  // [B,A,4]
    const float* pscores = (const float*)d_in[1];  // [B,A,C]
    const float* boxes   = (const float*)d_in[2];  // [B,M,4]
    const int*   labels  = (const int*)d_in[3];    // [B,M]
    const float* anchors = (const float*)d_in[4];  // [A,4]
    float*       out     = (float*)d_out;

    float* accf  = (float*)d_ws;
    int*   done  = (int*)d_ws + 3;
    int*   npt   = (int*)d_ws + 4;
    int*   n_pos = (int*)d_ws + 8;
    int*   buf   = (int*)d_ws + 8 + B;

    k_match<<<B, 1024, 0, stream>>>(boxes, labels, anchors, buf, n_pos, accf, done);
    constexpr int NQ = B * A / 4;                  // 279424 quads
    k_ce<<<(NQ + 255) / 256, 256, 0, stream>>>(plocs, pscores, boxes, anchors,
                                               buf, accf, n_pos, npt);
    k_topk<<<B, 512, 0, stream>>>((const float*)buf, n_pos, npt, accf, done, out);
}

// Round 12
// 289.387 us; speedup vs baseline: 1.5130x; 1.0507x over previous
//
#include <hip/hip_runtime.h>
#include <hip/hip_bf16.h>

// Problem constants (from reference setup_inputs)
constexpr int B = 128;
constexpr int A = 8732;
constexpr int C = 21;
constexpr int M = 8;

// workspace layout (4-byte elements):
// [0..2] accf  (0=conf_pos, 1=loc_sum, 2=conf_hard_neg)
// [3]    done  (k_topk completion counter)
// [4]    npt   (n_pos_total, written by k_ce block 0)
// [8..8+B)  n_pos
// [8+B ..)  packed/ce_neg buf [B*A]   (offset 544 B -> 16B aligned)

// ---------------------------------------------------------------------------
// K1: per-batch matching. One block (1024 threads) per batch row.
// Block 0 additionally zeroes the accumulators + completion counter (safe:
// nothing in k_match reads them; k_ce/k_topk run in later dispatches).
__global__ __launch_bounds__(1024) void k_match(
    const float* __restrict__ boxes,    // [B,M,4] raw pixel xy
    const int*   __restrict__ labels,   // [B,M]
    const float* __restrict__ anchors,  // [A,4] cxcy
    int*         __restrict__ packed,   // [B,A]  lab | (obj<<8)
    int*         __restrict__ n_pos,    // [B]
    float*       __restrict__ accf,
    int*         __restrict__ done)
{
    __shared__ float         s_iou[A];
    __shared__ unsigned char s_obj[A];
    __shared__ float s_pv[M][16];
    __shared__ int   s_pi[M][16];
    __shared__ int   s_force[M];
    __shared__ int   s_c[16];
    __shared__ float s_box[M][4];
    __shared__ int   s_lab[M];

    const int b = blockIdx.x;
    const int t = threadIdx.x;
    const int lane = t & 63;
    const int wv   = t >> 6;          // 0..15

    if (b == 0 && t == 0) {           // zero accumulators for this iteration
        accf[0] = 0.f; accf[1] = 0.f; accf[2] = 0.f; *done = 0;
    }

    if (t < M * 4) ((float*)s_box)[t] = boxes[b * M * 4 + t];
    if (t < M)     s_lab[t] = labels[b * M + t];
    __syncthreads();

    // scaled boxes (match reference: boxes / 300.0) + areas
    float bb[M][4], barea[M];
#pragma unroll
    for (int m = 0; m < M; m++) {
        bb[m][0] = s_box[m][0] / 300.f;
        bb[m][1] = s_box[m][1] / 300.f;
        bb[m][2] = s_box[m][2] / 300.f;
        bb[m][3] = s_box[m][3] / 300.f;
        barea[m] = (bb[m][2] - bb[m][0]) * (bb[m][3] - bb[m][1]);
    }

    float bestv[M];
    int   besti[M];
#pragma unroll
    for (int m = 0; m < M; m++) { bestv[m] = -1.f; besti[m] = 0; }

    const float4* anch4 = (const float4*)anchors;
    for (int a = t; a < A; a += 1024) {
        float4 an = anch4[a];
        float ax1 = an.x - an.z / 2.0f, ay1 = an.y - an.w / 2.0f;
        float ax2 = an.x + an.z / 2.0f, ay2 = an.y + an.w / 2.0f;
        float aarea = (ax2 - ax1) * (ay2 - ay1);

        float bmax = -1.f; int bm = 0;
#pragma unroll
        for (int m = 0; m < M; m++) {
            float lx = fmaxf(bb[m][0], ax1), ly = fmaxf(bb[m][1], ay1);
            float rx = fminf(bb[m][2], ax2), ry = fminf(bb[m][3], ay2);
            float iw = fmaxf(rx - lx, 0.f), ih = fmaxf(ry - ly, 0.f);
            float inter = iw * ih;
            float iou = inter / (barea[m] + aarea - inter);
            if (iou > bmax) { bmax = iou; bm = m; }               // first-max over m
            if (iou > bestv[m]) { bestv[m] = iou; besti[m] = a; } // first-max over a (ascending)
        }
        s_iou[a] = bmax;
        s_obj[a] = (unsigned char)bm;
    }

    // per-object argmax: wave shuffle reduce (tie-break: smaller anchor index)
#pragma unroll
    for (int m = 0; m < M; m++) {
        float v = bestv[m]; int i = besti[m];
        for (int off = 32; off > 0; off >>= 1) {
            float ov = __shfl_down(v, off);
            int   oi = __shfl_down(i, off);
            if (ov > v || (ov == v && oi < i)) { v = ov; i = oi; }
        }
        if (lane == 0) { s_pv[m][wv] = v; s_pi[m][wv] = i; }
    }
    __syncthreads();

    if (t < M) {
        float bv = -1.f; int bi = 0x7fffffff;
#pragma unroll
        for (int w = 0; w < 16; w++) {
            float v = s_pv[t][w]; int i = s_pi[t][w];
            if (v > bv || (v == bv && i < bi)) { bv = v; bi = i; }
        }
        s_force[t] = bi;
    }
    __syncthreads();

    // numpy fancy-assign semantics: last object wins on duplicate anchors
    if (t == 0) {
        for (int m = 0; m < M; m++) {
            int a = s_force[m];
            s_obj[a] = (unsigned char)m;
            s_iou[a] = 1.0f;
        }
    }
    __syncthreads();

    int cnt = 0;
    for (int a = t; a < A; a += 1024) {
        int obj = s_obj[a];
        int lab = s_lab[obj];
        if (s_iou[a] < 0.5f) lab = 0;
        packed[(size_t)b * A + a] = lab | (obj << 8);
        if (lab != 0) cnt++;
    }
    for (int off = 32; off > 0; off >>= 1) cnt += __shfl_down(cnt, off);
    if (lane == 0) s_c[wv] = cnt;
    __syncthreads();
    if (t == 0) {
        int c0 = 0;
#pragma unroll
        for (int w = 0; w < 16; w++) c0 += s_c[w];
        n_pos[b] = c0;
    }
}

// ---------------------------------------------------------------------------
// K2: per-anchor CE + positive loc L1. One thread per 4 consecutive anchors:
// 84 floats = 21 aligned float4 loads (best measured form: 122 µs; six
// alternative structures — LDS+barrier, reg-pipeline, DMA-dbuf, scalar/row,
// wave-coop, nontemporal — all measured >= this). Block 0's first wave
// additionally reduces n_pos -> npt.
__global__ __launch_bounds__(256) void k_ce(
    const float* __restrict__ plocs,    // [B,A,4]
    const float* __restrict__ pscores,  // [B,A,C]
    const float* __restrict__ boxes,    // [B,M,4] raw pixel xy
    const float* __restrict__ anchors,  // [A,4]
    int*         __restrict__ buf,      // in: packed, out: ce_neg bits
    float*       __restrict__ accf,
    const int*   __restrict__ n_pos,    // [B]
    int*         __restrict__ npt)      // out: n_pos_total
{
    if (blockIdx.x == 0 && threadIdx.x < 64) {
        int v = n_pos[threadIdx.x] + n_pos[threadIdx.x + 64];
        for (int off = 32; off > 0; off >>= 1) v += __shfl_down(v, off);
        if (threadIdx.x == 0) *npt = v;
    }

    constexpr int NQ = B * A / 4;       // 279424 quads
    const int i4 = blockIdx.x * 256 + threadIdx.x;
    float l_pos = 0.f, l_loc = 0.f;

    if (i4 < NQ) {
        const int base = i4 * 4;        // flat anchor index of quad start
        const float4* s4 = (const float4*)(pscores + (size_t)base * C);
        float4 v[21];
#pragma unroll
        for (int i = 0; i < 21; i++) v[i] = s4[i];   // 336 B contiguous
        const float* f = (const float*)v;            // 84 floats

        int4 pk4 = ((const int4*)buf)[i4];
        const int pks[4] = {pk4.x, pk4.y, pk4.z, pk4.w};

        const int b = base / A;
        const int a0 = base - b * A;

        float4 cn4;
        float* cn = (float*)&cn4;
#pragma unroll
        for (int j = 0; j < 4; j++) {
            const float* row = f + j * C;
            const int lab = pks[j] & 255;
            const int obj = pks[j] >> 8;

            float mx = row[0];
#pragma unroll
            for (int c = 1; c < C; c++) mx = fmaxf(mx, row[c]);
            float sum = 0.f, slab = 0.f;
#pragma unroll
            for (int c = 0; c < C; c++) {
                sum += __expf(row[c] - mx);
                if (c == lab) slab = row[c];
            }
            float ce = mx + __logf(sum) - slab;

            cn[j] = ce;
            if (lab != 0) {
                cn[j] = 0.f;
                l_pos += ce;
                const float* bx = boxes + ((size_t)b * M + obj) * 4;
                const float* an = anchors + (size_t)(a0 + j) * 4;
                // reference quirk: raw pixel xy boxes fed into cxcy_to_gcxgcy
                float dx = (bx[0] - an[0]) / (an[2] / 10.f);
                float dy = (bx[1] - an[1]) / (an[3] / 10.f);
                float dw = logf(bx[2] / an[2]) * 5.f;
                float dh = logf(bx[3] / an[3]) * 5.f;
                float4 p = ((const float4*)plocs)[base + j];
                l_loc += fabsf(p.x - dx) + fabsf(p.y - dy) +
                         fabsf(p.z - dw) + fabsf(p.w - dh);
            }
        }
        ((float4*)buf)[i4] = cn4;
    }

    // wave reduce; positives are rare so atomics are rare
    for (int off = 32; off > 0; off >>= 1) {
        l_pos += __shfl_down(l_pos, off);
        l_loc += __shfl_down(l_loc, off);
    }
    if ((threadIdx.x & 63) == 0 && (l_pos != 0.f || l_loc != 0.f)) {
        atomicAdd(&accf[0], l_pos);
        atomicAdd(&accf[1], l_loc);
    }
}

// ---------------------------------------------------------------------------
// K3: per-row sum of top-(3*n_pos[b]) of ce_neg via radix select, FUSED with
// the final scalar (completion-counter pattern; device-scope atomics).
// Per-wave histograms whist[16][257] (bank-rotated) avoid the cross-wave
// same-address serialization on the concentrated CE exponent bins.
// Exact even with ties: sum = sum(v>t) + (K - cnt_gt) * t.
__global__ __launch_bounds__(1024) void k_topk(
    const float* __restrict__ ce_neg,   // [B,A] (aliased buf)
    const int*   __restrict__ n_pos,    // [B]
    const int*   __restrict__ npt,      // n_pos_total (from k_ce)
    float*       __restrict__ accf,     // accf[2] += row topK sum
    int*         __restrict__ done,     // completion counter (zeroed by k_match)
    float*       __restrict__ out)
{
    __shared__ unsigned int vals[A];
    __shared__ unsigned int hist[256];      // merged histogram -> suffix sums
    __shared__ unsigned int whist[16][257]; // per-wave histograms (padded)
    __shared__ unsigned int s_prefix, s_krem;
    __shared__ float        rs[16];
    __shared__ unsigned int rc[16];

    const int b = blockIdx.x;
    const int t = threadIdx.x;
    const int lane = t & 63;
    const int wv   = t >> 6;
    const int K = 3 * n_pos[b];
    const float* row = ce_neg + (size_t)b * A;

    {   // coalesced uint4 load (A = 4*2183, row base 16B-aligned)
        const uint4* r4 = (const uint4*)row;
        uint4* v4 = (uint4*)vals;
        for (int i = t; i < A / 4; i += 1024) v4[i] = r4[i];
    }
    if (t == 0) { s_prefix = 0u; s_krem = (unsigned)K; }
    __syncthreads();

    float blockSum = 0.f;                   // valid at t==0

    if (K >= A) {        // uniform branch: sum the whole row
        float s = 0.f;
        for (int i = t; i < A; i += 1024) s += __uint_as_float(vals[i]);
        for (int off = 32; off > 0; off >>= 1) s += __shfl_down(s, off);
        if (lane == 0) rs[wv] = s;
        __syncthreads();
        if (t == 0) {
            float tot = 0.f;
#pragma unroll
            for (int w = 0; w < 16; w++) tot += rs[w];
            blockSum = tot;
        }
    } else if (K > 0) {
        for (int pass = 0; pass < 4; pass++) {
            const int shift = 24 - 8 * pass;
            const unsigned pref = s_prefix;
            const unsigned krem = s_krem;
            // zero per-wave histograms
            unsigned* wf = &whist[0][0];
            for (int i = t; i < 16 * 257; i += 1024) wf[i] = 0u;
            __syncthreads();
            for (int i = t; i < A; i += 1024) {
                unsigned int v = vals[i];
                if (pass == 0 || (v >> (shift + 8)) == pref)
                    atomicAdd(&whist[wv][(v >> shift) & 255u], 1u);
            }
            __syncthreads();
            // merge 16 per-wave hists (lanes read distinct banks, 2/bank)
            if (t < 256) {
                unsigned s0 = 0;
#pragma unroll
                for (int w = 0; w < 16; w++) s0 += whist[w][t];
                hist[t] = s0;
            }
            __syncthreads();
            // wave-0 suffix scan of the 256 bins (hist[i] := sum hist[i..255])
            if (t < 64) {
                unsigned h0 = hist[4 * t + 0], h1 = hist[4 * t + 1];
                unsigned h2 = hist[4 * t + 2], h3 = hist[4 * t + 3];
                unsigned s3 = h3, s2 = h2 + s3, s1 = h1 + s2, s0 = h0 + s1;
                unsigned suf = s0;                 // inclusive suffix of lane totals
                for (int off = 1; off < 64; off <<= 1) {
                    unsigned o = __shfl_down(suf, off);
                    if (t + off < 64) suf += o;
                }
                unsigned above = suf - s0;         // totals of lanes > t
                hist[4 * t + 0] = above + s0;
                hist[4 * t + 1] = above + s1;
                hist[4 * t + 2] = above + s2;
                hist[4 * t + 3] = above + s3;
            }
            __syncthreads();
            if (t < 256) {
                unsigned ssT = hist[t];
                unsigned ssN = (t < 255) ? hist[t + 1] : 0u;
                if (ssT >= krem && ssN < krem) {   // exactly one thread
                    s_prefix = (pref << 8) | (unsigned)t;
                    s_krem   = krem - ssN;
                }
            }
            __syncthreads();
        }

        const unsigned int tb = s_prefix;  // bits of the K-th largest value
        float sg = 0.f; unsigned int cg = 0;
        for (int i = t; i < A; i += 1024) {
            unsigned int v = vals[i];
            if (v > tb) { sg += __uint_as_float(v); cg++; }
        }
        for (int off = 32; off > 0; off >>= 1) {
            sg += __shfl_down(sg, off);
            cg += __shfl_down(cg, off);
        }
        if (lane == 0) { rs[wv] = sg; rc[wv] = cg; }
        __syncthreads();
        if (t == 0) {
            float tv = __uint_as_float(tb);
            float tot = 0.f; unsigned cnt = 0;
#pragma unroll
            for (int w = 0; w < 16; w++) { tot += rs[w]; cnt += rc[w]; }
            blockSum = tot + (float)(K - (int)cnt) * tv;
        }
    }
    // K <= 0: blockSum stays 0, still participate in completion protocol.

    if (t == 0) {
        if (blockSum != 0.f) atomicAdd(&accf[2], blockSum);
        __threadfence();                       // order my add before the count
        unsigned old = atomicAdd((unsigned*)done, 1u);
        if (old == (unsigned)(B - 1)) {        // last block: final scalar
            float cpos = atomicAdd(&accf[0], 0.f);   // device-coherent reads
            float lsum = atomicAdd(&accf[1], 0.f);
            float chn  = atomicAdd(&accf[2], 0.f);
            float n = (float)(*npt);
            out[0] = (chn + cpos) / n + lsum / (n * 4.f);
        }
    }
}

// ---------------------------------------------------------------------------
extern "C" void kernel_launch(void* const* d_in, const int* in_sizes, int n_in,
                              void* d_out, int out_size, void* d_ws, size_t ws_size,
                              hipStream_t stream)
{
    const float* plocs   = (const float*)d_in[0];  // [B,A,4]
    const float* pscores = (const float*)d_in[1];  // [B,A,C]
    const float* boxes   = (const float*)d_in[2];  // [B,M,4]
    const int*   labels  = (const int*)d_in[3];    // [B,M]
    const float* anchors = (const float*)d_in[4];  // [A,4]
    float*       out     = (float*)d_out;

    float* accf  = (float*)d_ws;
    int*   done  = (int*)d_ws + 3;
    int*   npt   = (int*)d_ws + 4;
    int*   n_pos = (int*)d_ws + 8;
    int*   buf   = (int*)d_ws + 8 + B;

    k_match<<<B, 1024, 0, stream>>>(boxes, labels, anchors, buf, n_pos, accf, done);
    constexpr int NQ = B * A / 4;
    k_ce<<<(NQ + 255) / 256, 256, 0, stream>>>(plocs, pscores, boxes, anchors,
                                               buf, accf, n_pos, npt);
    k_topk<<<B, 1024, 0, stream>>>((const float*)buf, n_pos, npt, accf, done, out);
}